// Round 8
// baseline (115.760 us; speedup 1.0000x reference)
//
#include <hip/hip_runtime.h>
#include <hip/hip_bf16.h>

// Wide_BasicBlock_Q: DoReFa-quantized residual block on MI355X (gfx950).
// Round 7: convs restructured around a one-shot LDS input slab.
//   - block = 128 co x 64 pos (grid 1024, 4 blocks/CU, 36-38 KB LDS)
//   - B: input window staged ONCE into LDS (zero-padded, XOR-swizzled);
//     K-loop reads B from LDS only (x9 reuse across kh,kw), no re-staging
//   - A: weights loaded straight to registers (coalesced, L2-hot),
//     1-step register prefetch; NO barriers in the K-loop
//   - shortcut fused as 2 tail K-steps from a swizzled asc mini-slab

typedef __bf16 bf16x8 __attribute__((ext_vector_type(8)));
typedef float f32x4 __attribute__((ext_vector_type(4)));

#define EPSV 1e-5f

__global__ void k_init(float* wmax) {
    if (threadIdx.x < 2) wmax[threadIdx.x] = 0.f;
}

// max|w| per tensor (tanh is monotonic: max|tanh(w)| = tanh(max|w|))
__global__ __launch_bounds__(256) void k_wmax(const float* __restrict__ w1,
                                              const float* __restrict__ w2,
                                              float* wmax) {
    int sel = blockIdx.x >> 4;                 // 0: w1, 1: w2
    const float* src = sel ? w2 : w1;
    int cnt = sel ? 128 * 128 * 9 : 128 * 64 * 9;
    float m = 0.f;
    for (int i = (blockIdx.x & 15) * 256 + threadIdx.x; i < cnt; i += 16 * 256)
        m = fmaxf(m, fabsf(src[i]));
#pragma unroll
    for (int off = 32; off > 0; off >>= 1)
        m = fmaxf(m, __shfl_down(m, off));
    __shared__ float red[4];
    if ((threadIdx.x & 63) == 0) red[threadIdx.x >> 6] = m;
    __syncthreads();
    if (threadIdx.x == 0) {
        m = fmaxf(fmaxf(red[0], red[1]), fmaxf(red[2], red[3]));
        atomicMax((int*)(wmax + sel), __float_as_int(m));  // all values >= 0
    }
}

// bnp layout (floats): [0:64)=sc1 [64:128)=sh1 [128:192)=scs [192:256)=shs
//                      [256:384)=sc2 [384:512)=sh2
__global__ void k_bnprep(const float* g1, const float* b1, const float* m1, const float* v1,
                         const float* g2, const float* b2, const float* m2, const float* v2,
                         const float* gs, const float* bs, const float* ms, const float* vs,
                         float* bnp) {
    int c = threadIdx.x;  // blockDim = 128
    if (c < 64) {
        float s = g1[c] * rsqrtf(v1[c] + EPSV);
        bnp[c] = s;          bnp[64 + c] = b1[c] - m1[c] * s;
        float s2 = gs[c] * rsqrtf(vs[c] + EPSV);
        bnp[128 + c] = s2;   bnp[192 + c] = bs[c] - ms[c] * s2;
    }
    float s = g2[c] * rsqrtf(v2[c] + EPSV);
    bnp[256 + c] = s;        bnp[384 + c] = b2[c] - m2[c] * s;
}

// Quantize (DoReFa) + prepack weights: dst[((s*128 + co)*32 + kk)] with
// k = s*32+kk, k-order = khw*CIN + ci, src layout [co][ci][kh][kw].
template <int CIN, int KHW, bool QUANT>
__global__ __launch_bounds__(256) void k_wq(const float* __restrict__ w,
                                            __bf16* __restrict__ dst,
                                            const float* __restrict__ wmax, int total) {
    int idx = blockIdx.x * 256 + threadIdx.x;
    if (idx >= total) return;
    int kk = idx & 31;
    int co = (idx >> 5) & 127;
    int s = idx >> 12;
    int k = s * 32 + kk;
    int khw = k / CIN;
    int ci = k % CIN;
    float v = w[(co * CIN + ci) * KHW + khw];
    float outv;
    if constexpr (QUANT) {
        float M = tanhf(*wmax);                          // max|tanh(w)|
        float t = tanhf(v) / (2.f * M) + 0.5f;           // in [0,1]
        outv = 2.f * (rintf(t * 15.f) * (1.f / 15.f)) - 1.f;
    } else {
        outv = v;
    }
    dst[idx] = (__bf16)outv;
}

// a1 = actq4(bn1(x)) -> NHWC bf16 [256][32][32][64]
// asc = bn_s(x) at even (h,w) -> NHWC bf16 [256][16][16][64]
__global__ __launch_bounds__(256) void k_a1(const float* __restrict__ x,
                                            const float* __restrict__ bnp,
                                            __bf16* __restrict__ a1,
                                            __bf16* __restrict__ asc) {
    __shared__ __align__(16) __bf16 l1[32][72];
    __shared__ __align__(16) __bf16 l2[16][72];
    __shared__ float s1[64], h1[64], ss[64], hs[64];
    int t = threadIdx.x;
    int n = blockIdx.x >> 5, h = blockIdx.x & 31;
    if (t < 64) {
        s1[t] = bnp[t];       h1[t] = bnp[64 + t];
        ss[t] = bnp[128 + t]; hs[t] = bnp[192 + t];
    }
    __syncthreads();
    bool he = (h & 1) == 0;
#pragma unroll
    for (int i = 0; i < 2; ++i) {
        int idx = t + i * 256;          // over (c,w4): c=idx>>3, w0=(idx&7)*4
        int c = idx >> 3, w0 = (idx & 7) * 4;
        float4 xv = *(const float4*)(x + (((size_t)(n * 64 + c) * 32 + h) * 32 + w0));
        float xa[4] = {xv.x, xv.y, xv.z, xv.w};
#pragma unroll
        for (int k = 0; k < 4; ++k) {
            float v = xa[k] * s1[c] + h1[c];
            float q = rintf(fminf(fmaxf(v, 0.f), 1.f) * 15.f) * (1.f / 15.f);
            l1[w0 + k][c] = (__bf16)q;
        }
        if (he) {
            l2[w0 >> 1][c]       = (__bf16)(xa[0] * ss[c] + hs[c]);
            l2[(w0 >> 1) + 1][c] = (__bf16)(xa[2] * ss[c] + hs[c]);
        }
    }
    __syncthreads();
    {
        int o = t * 8;                  // over (w,c): w=o>>6, c=o&63
        int w = o >> 6, c = o & 63;
        *(uint4*)(a1 + (((size_t)(n * 32 + h)) * 32 + w) * 64 + c) = *(uint4*)&l1[w][c];
    }
    if (he) {
        int o = t * 4;
        int w2 = o >> 6, c = o & 63;
        *(uint2*)(asc + (((size_t)(n * 16 + (h >> 1))) * 16 + w2) * 64 + c) = *(uint2*)&l2[w2][c];
    }
}

// Implicit-GEMM conv via MFMA 16x16x32 bf16 — LDS input-slab structure.
// Block: 128 co x 64 pos (4 out-rows x 16); 4 waves (2co x 2pos), each wave
// 64co x 32pos (acc 4x2, 8 MFMA/K-step). Grid = 65536/64 = 1024.
// Slab: [3S+3][15S+3][CIN] bf16, zero-padded borders, staged once.
//   Swizzle: chunk byte-offset within cell ^= ((slab_w >> (S-1)) & 7) << 4
//   (read-side fragment gathers then hit ~2-way banks = free).
// Weights: per K-step 4x 16B register loads per lane (coalesced, L2-hot),
// 1-step prefetch. No barriers in the K-loop.
// Shortcut tail (KS_SC>0): 2 K-steps from swizzled asc mini-slab [64 cells].
// MODE 0: epilogue bn2+actq4 -> a2out (NHWC bf16); MODE 1: dout (fp32 NCHW).
template <int CIN, int KS_MAIN, int KS_SC, int STRIDE, int HIN, int MODE>
__global__ __launch_bounds__(256, 4) void conv_mfma(
        const __bf16* __restrict__ act, const __bf16* __restrict__ actsc,
        const __bf16* __restrict__ wq,
        const float* __restrict__ sc2, const float* __restrict__ sh2,
        __bf16* __restrict__ a2out, float* __restrict__ dout) {
    constexpr int SLAB_H = 3 * STRIDE + 3;
    constexpr int SLAB_W = 15 * STRIDE + 3;
    constexpr int CELLB = CIN * 2;          // bytes per (h,w) cell
    constexpr int CPC = CIN / 8;            // 16B chunks per cell
    constexpr int NCH = SLAB_H * SLAB_W * CPC;
    __shared__ __align__(16) __bf16 slab[SLAB_H][SLAB_W][CIN];
    __shared__ __align__(16) __bf16 scslab[(KS_SC > 0) ? 4 * 16 * 64 : 8];

    const int t = threadIdx.x;
    const int wv = t >> 6, l = t & 63;
    const int wco = wv >> 1, wp = wv & 1;
    const int lrow = l & 15, half = l >> 4;
    const int pbase = blockIdx.x * 64;
    const int n = pbase >> 8;
    const int rbase = pbase & 255;          // 4-row band within 16x16 image
    const int h2_0 = rbase >> 4;
    const int hb = STRIDE * h2_0 - 1;       // slab h origin in input coords

    char* sbytes = (char*)&slab[0][0][0];
    // ---- stage main slab (once) ----
    for (int c = t; c < NCH; c += 256) {
        int sub = c & (CPC - 1);
        int cell = c / CPC;
        int w = cell % SLAB_W;
        int h = cell / SLAB_W;
        int hi = hb + h, wi = w - 1;
        uint4 v = {0u, 0u, 0u, 0u};
        if ((unsigned)hi < (unsigned)HIN && (unsigned)wi < (unsigned)HIN)
            v = *(const uint4*)(act + ((size_t)(n * HIN + hi) * HIN + wi) * CIN + sub * 8);
        int key = ((w >> (STRIDE - 1)) & 7) << 4;
        *(uint4*)(sbytes + cell * CELLB + ((sub * 16) ^ key)) = v;
    }
    if constexpr (KS_SC > 0) {
        char* scb = (char*)&scslab[0];
        for (int c = t; c < 512; c += 256) {
            int sub = c & 7, cell = c >> 3;
            int w2 = cell & 15, h2l = cell >> 4;
            uint4 v = *(const uint4*)(actsc +
                ((size_t)(n * 16 + h2_0 + h2l) * 16 + w2) * 64 + sub * 8);
            *(uint4*)(scb + cell * 128 + ((sub * 16) ^ ((w2 & 7) << 4))) = v;
        }
    }
    __syncthreads();                         // slab ready; read-only hereafter

    constexpr int CPS = CIN / 32;            // ci-chunks per (kh,kw)
    constexpr int KS = KS_MAIN + KS_SC;
    f32x4 acc[4][2] = {};

    const __bf16* gAbase = wq + ((wco * 64 + lrow) * 32 + half * 8);
    auto loadA = [&](int s, bf16x8* dst) {
        const __bf16* g = gAbase + (size_t)s * 4096;
#pragma unroll
        for (int i = 0; i < 4; ++i) dst[i] = *(const bf16x8*)(g + i * 512);
    };
    auto loadB = [&](int s, bf16x8* bfr) {
        if (KS_SC == 0 || s < KS_MAIN) {
            int khw = s / CPS;
            int ci0 = (s & (CPS - 1)) * 32;
            int kh = khw / 3, kw = khw - kh * 3;
            int cib = (ci0 + half * 8) * 2;
#pragma unroll
            for (int j = 0; j < 2; ++j) {
                int sh = STRIDE * (wp * 2 + j) + kh;
                int sw = STRIDE * lrow + kw;
                int key = ((sw >> (STRIDE - 1)) & 7) << 4;
                bfr[j] = *(const bf16x8*)(sbytes + (sh * SLAB_W + sw) * CELLB + (cib ^ key));
            }
        } else {
            int cib = ((s - KS_MAIN) * 32 + half * 8) * 2;
            int key = (lrow & 7) << 4;
#pragma unroll
            for (int j = 0; j < 2; ++j) {
                int pl = wp * 32 + j * 16 + lrow;
                bfr[j] = *(const bf16x8*)((char*)&scslab[0] + pl * 128 + (cib ^ key));
            }
        }
    };
    auto mfma8 = [&](bf16x8* af, bf16x8* bfr) {
        __builtin_amdgcn_s_setprio(1);
#pragma unroll
        for (int i = 0; i < 4; ++i)
#pragma unroll
            for (int j = 0; j < 2; ++j)
                acc[i][j] = __builtin_amdgcn_mfma_f32_16x16x32_bf16(af[i], bfr[j], acc[i][j], 0, 0, 0);
        __builtin_amdgcn_s_setprio(0);
    };

    bf16x8 aA[4], aB[4], bfr[2];
    loadA(0, aA);
    for (int s = 0; s < KS; s += 2) {
        if (s + 1 < KS) loadA(s + 1, aB);    // prefetch next weights to regs
        loadB(s, bfr);
        mfma8(aA, bfr);
        if (s + 1 < KS) {
            if (s + 2 < KS) loadA(s + 2, aA);
            loadB(s + 1, bfr);
            mfma8(aB, bfr);
        }
    }

    // epilogue: C/D layout col=lane&15 (pos), row=(lane>>4)*4+reg (co)
#pragma unroll
    for (int i = 0; i < 4; ++i) {
        const int co0 = wco * 64 + i * 16 + half * 4;
        float s2[4], h2v[4];
        if constexpr (MODE == 0) {
#pragma unroll
            for (int r = 0; r < 4; ++r) { s2[r] = sc2[co0 + r]; h2v[r] = sh2[co0 + r]; }
        }
#pragma unroll
        for (int j = 0; j < 2; ++j) {
            const int rr = rbase + wp * 32 + j * 16 + lrow;
            if constexpr (MODE == 0) {
                __bf16 tmp[4];
#pragma unroll
                for (int r = 0; r < 4; ++r) {
                    float v = acc[i][j][r] * s2[r] + h2v[r];
                    tmp[r] = (__bf16)(rintf(fminf(fmaxf(v, 0.f), 1.f) * 15.f) * (1.f / 15.f));
                }
                *(uint2*)(a2out + ((size_t)n * 256 + rr) * 128 + co0) = *(uint2*)tmp;
            } else {
#pragma unroll
                for (int r = 0; r < 4; ++r)
                    dout[((size_t)n * 128 + co0 + r) * 256 + rr] = acc[i][j][r];
            }
        }
    }
}

extern "C" void kernel_launch(void* const* d_in, const int* in_sizes, int n_in,
                              void* d_out, int out_size, void* d_ws, size_t ws_size,
                              hipStream_t stream) {
    const float* x   = (const float*)d_in[0];
    const float* w1  = (const float*)d_in[1];
    const float* w2  = (const float*)d_in[2];
    const float* wsw = (const float*)d_in[3];
    const float* g1  = (const float*)d_in[4];
    const float* b1  = (const float*)d_in[5];
    const float* m1  = (const float*)d_in[6];
    const float* v1  = (const float*)d_in[7];
    const float* g2  = (const float*)d_in[8];
    const float* b2  = (const float*)d_in[9];
    const float* m2  = (const float*)d_in[10];
    const float* v2  = (const float*)d_in[11];
    const float* gs  = (const float*)d_in[12];
    const float* bs  = (const float*)d_in[13];
    const float* ms  = (const float*)d_in[14];
    const float* vs  = (const float*)d_in[15];
    float* out = (float*)d_out;
    char* ws = (char*)d_ws;

    // ws layout (bytes)
    __bf16* a1  = (__bf16*)(ws + 64);                   // 256*32*32*64 bf16 = 32 MiB
    __bf16* a2  = (__bf16*)(ws + 64 + 33554432);        // 256*16*16*128 bf16 = 16 MiB
    __bf16* asc = (__bf16*)(ws + 64 + 50331648);        // 256*16*16*64 bf16 = 8 MiB
    __bf16* w1q = (__bf16*)(ws + 64 + 58720256);        // 18*128*32 bf16
    __bf16* w2q = (__bf16*)(ws + 64 + 58867712);        // 38*128*32 bf16 (w2 + ws tail)
    float*  bnp = (float*)(ws + 64 + 59179008);         // 512 floats
    float* wmax = (float*)(ws + 64 + 59181056);         // 2 floats

    k_init<<<1, 64, 0, stream>>>(wmax);
    k_wmax<<<32, 256, 0, stream>>>(w1, w2, wmax);
    k_bnprep<<<1, 128, 0, stream>>>(g1, b1, m1, v1, g2, b2, m2, v2, gs, bs, ms, vs, bnp);
    k_wq<64, 9, true><<<288, 256, 0, stream>>>(w1, w1q, wmax, 73728);
    k_wq<128, 9, true><<<576, 256, 0, stream>>>(w2, w2q, wmax + 1, 147456);
    k_wq<64, 1, false><<<32, 256, 0, stream>>>(wsw, w2q + 36 * 4096, nullptr, 8192);
    k_a1<<<8192, 256, 0, stream>>>(x, bnp, a1, asc);
    // conv1: 3x3 stride 2 pad 1 on a1 (K=576); epilogue bn2+actq4 -> a2
    conv_mfma<64, 18, 0, 2, 32, 0><<<1024, 256, 0, stream>>>(
        a1, nullptr, w1q, bnp + 256, bnp + 384, a2, nullptr);
    // conv2: 3x3 stride 1 pad 1 on a2 (K=1152) + fused 1x1 shortcut (K=64) -> out
    conv_mfma<128, 36, 2, 1, 16, 1><<<1024, 256, 0, stream>>>(
        a2, asc, w2q, nullptr, nullptr, nullptr, out);
}

// Round 9
// 85.749 us; speedup vs baseline: 1.3500x; 1.3500x over previous
//
#include <hip/hip_runtime.h>
#include <hip/hip_bf16.h>

// Wide_BasicBlock_Q: DoReFa-quantized residual block on MI355X (gfx950).
// Round 8: exact integer main path.
//   - a1/a2 stored as i8 ints (0..15); weights as i8 odd ints (-15..15)
//   - convs use mfma_i32_16x16x64_i8 (K=64/instr, i32-exact), epilogue *1/225
//   - shortcut remains bf16: 2-step mfma_f32_16x16x32_bf16 tail, f32 acc
//   - B: one-shot LDS input slab (i8, XOR-swizzled); A: weights global->reg
//   - K-loop fully unrolled at compile time (no divides, no barriers);
//     compiler free to deep-pipeline weight loads

typedef __bf16 bf16x8 __attribute__((ext_vector_type(8)));
typedef float f32x4 __attribute__((ext_vector_type(4)));
typedef int i32x4 __attribute__((ext_vector_type(4)));

#define EPSV 1e-5f

__global__ void k_init(float* wmax) {
    if (threadIdx.x < 2) wmax[threadIdx.x] = 0.f;
}

// max|w| per tensor (tanh is monotonic: max|tanh(w)| = tanh(max|w|))
__global__ __launch_bounds__(256) void k_wmax(const float* __restrict__ w1,
                                              const float* __restrict__ w2,
                                              float* wmax) {
    int sel = blockIdx.x >> 4;                 // 0: w1, 1: w2
    const float* src = sel ? w2 : w1;
    int cnt = sel ? 128 * 128 * 9 : 128 * 64 * 9;
    float m = 0.f;
    for (int i = (blockIdx.x & 15) * 256 + threadIdx.x; i < cnt; i += 16 * 256)
        m = fmaxf(m, fabsf(src[i]));
#pragma unroll
    for (int off = 32; off > 0; off >>= 1)
        m = fmaxf(m, __shfl_down(m, off));
    __shared__ float red[4];
    if ((threadIdx.x & 63) == 0) red[threadIdx.x >> 6] = m;
    __syncthreads();
    if (threadIdx.x == 0) {
        m = fmaxf(fmaxf(red[0], red[1]), fmaxf(red[2], red[3]));
        atomicMax((int*)(wmax + sel), __float_as_int(m));  // all values >= 0
    }
}

// bnp layout (floats): [0:64)=sc1 [64:128)=sh1 [128:192)=scs [192:256)=shs
//                      [256:384)=sc2 [384:512)=sh2
__global__ void k_bnprep(const float* g1, const float* b1, const float* m1, const float* v1,
                         const float* g2, const float* b2, const float* m2, const float* v2,
                         const float* gs, const float* bs, const float* ms, const float* vs,
                         float* bnp) {
    int c = threadIdx.x;  // blockDim = 128
    if (c < 64) {
        float s = g1[c] * rsqrtf(v1[c] + EPSV);
        bnp[c] = s;          bnp[64 + c] = b1[c] - m1[c] * s;
        float s2 = gs[c] * rsqrtf(vs[c] + EPSV);
        bnp[128 + c] = s2;   bnp[192 + c] = bs[c] - ms[c] * s2;
    }
    float s = g2[c] * rsqrtf(v2[c] + EPSV);
    bnp[256 + c] = s;        bnp[384 + c] = b2[c] - m2[c] * s;
}

// i8 weight quant+pack: dst[(s*128 + co)*64 + kk], k = s*64+kk,
// k-order = khw*CIN + ci, src layout [co][ci][3][3]. Values = 2j-15, j=0..15.
template <int CIN>
__global__ __launch_bounds__(256) void k_wq_i8(const float* __restrict__ w,
                                               signed char* __restrict__ dst,
                                               const float* __restrict__ wmax, int total) {
    int idx = blockIdx.x * 256 + threadIdx.x;
    if (idx >= total) return;
    int kk = idx & 63;
    int co = (idx >> 6) & 127;
    int s = idx >> 13;
    int k = s * 64 + kk;
    int khw = k / CIN;
    int ci = k % CIN;
    float v = w[(co * CIN + ci) * 9 + khw];
    float M = tanhf(*wmax);                          // max|tanh(w)|
    float t = tanhf(v) / (2.f * M) + 0.5f;           // in [0,1]
    int j = (int)rintf(t * 15.f);
    dst[idx] = (signed char)(2 * j - 15);
}

// bf16 pack (shortcut weights, unquantized): dst[(s*128+co)*32+kk], K32 layout
__global__ __launch_bounds__(256) void k_wq_bf(const float* __restrict__ w,
                                               __bf16* __restrict__ dst, int total) {
    int idx = blockIdx.x * 256 + threadIdx.x;
    if (idx >= total) return;
    int kk = idx & 31;
    int co = (idx >> 5) & 127;
    int s = idx >> 12;
    int ci = s * 32 + kk;                            // 1x1 conv: k = ci
    dst[idx] = (__bf16)w[co * 64 + ci];
}

// a1 = round(15*actq) ints -> NHWC i8 [256][32][32][64]
// asc = bn_s(x) at even (h,w) -> NHWC bf16 [256][16][16][64]
__global__ __launch_bounds__(256) void k_a1(const float* __restrict__ x,
                                            const float* __restrict__ bnp,
                                            signed char* __restrict__ a1,
                                            __bf16* __restrict__ asc) {
    __shared__ __align__(16) signed char l1[32][80];
    __shared__ __align__(16) __bf16 l2[16][72];
    __shared__ float s1[64], h1[64], ss[64], hs[64];
    int t = threadIdx.x;
    int n = blockIdx.x >> 5, h = blockIdx.x & 31;
    if (t < 64) {
        s1[t] = bnp[t];       h1[t] = bnp[64 + t];
        ss[t] = bnp[128 + t]; hs[t] = bnp[192 + t];
    }
    __syncthreads();
    bool he = (h & 1) == 0;
#pragma unroll
    for (int i = 0; i < 2; ++i) {
        int idx = t + i * 256;          // over (c,w4): c=idx>>3, w0=(idx&7)*4
        int c = idx >> 3, w0 = (idx & 7) * 4;
        float4 xv = *(const float4*)(x + (((size_t)(n * 64 + c) * 32 + h) * 32 + w0));
        float xa[4] = {xv.x, xv.y, xv.z, xv.w};
#pragma unroll
        for (int k = 0; k < 4; ++k) {
            float v = xa[k] * s1[c] + h1[c];
            l1[w0 + k][c] = (signed char)(int)rintf(fminf(fmaxf(v, 0.f), 1.f) * 15.f);
        }
        if (he) {
            l2[w0 >> 1][c]       = (__bf16)(xa[0] * ss[c] + hs[c]);
            l2[(w0 >> 1) + 1][c] = (__bf16)(xa[2] * ss[c] + hs[c]);
        }
    }
    __syncthreads();
    {
        int o = t * 8;                  // over (w,c): w=o>>6, c=o&63
        int w = o >> 6, c = o & 63;
        *(uint2*)(a1 + (((size_t)(n * 32 + h)) * 32 + w) * 64 + c) = *(uint2*)&l1[w][c];
    }
    if (he) {
        int o = t * 4;
        int w2 = o >> 6, c = o & 63;
        *(uint2*)(asc + (((size_t)(n * 16 + (h >> 1))) * 16 + w2) * 64 + c) = *(uint2*)&l2[w2][c];
    }
}

// Implicit-GEMM conv via MFMA i32_16x16x64_i8 — LDS slab, unrolled K-loop.
// Block: 128 co x 64 pos (4 out-rows x 16); 4 waves (2co x 2pos), each wave
// 64co x 32pos (acc 4x2, 8 MFMA/K64-step). Grid 1024.
// Slab: [3S+3][15S+3][CIN] i8, zero-padded, chunk-XOR swizzle (16B chunks).
// Weights: per step 4x 16B register loads/lane, K-loop fully unrolled ->
// compiler hoists loads deep (ILP vs L2 latency). No barriers in loop.
// i8 frag layout (16x16x64): lane row=l&15, k = (l>>4)*16 + e (16B contiguous).
// Shortcut tail (KS_SC>0): bf16 16x16x32 steps from swizzled asc mini-slab
// into separate f32 acc. Epilogue: main = accI/225 (exact ints in accI).
// MODE 0: bn2+actq4 -> a2out ints (NHWC i8); MODE 1: dout fp32 NCHW (+sc).
template <int CIN, int KS_MAIN, int KS_SC, int STRIDE, int HIN, int MODE>
__global__ __launch_bounds__(256, 4) void conv_mfma(
        const signed char* __restrict__ act, const __bf16* __restrict__ actsc,
        const signed char* __restrict__ wqi, const __bf16* __restrict__ wsc,
        const float* __restrict__ sc2, const float* __restrict__ sh2,
        signed char* __restrict__ a2out, float* __restrict__ dout) {
    constexpr int SLAB_H = 3 * STRIDE + 3;
    constexpr int SLAB_W = 15 * STRIDE + 3;
    constexpr int CPC = CIN / 16;            // 16B chunks per (h,w) cell
    constexpr int NCH = SLAB_H * SLAB_W * CPC;
    __shared__ __align__(16) signed char slab[SLAB_H * SLAB_W * CIN];
    __shared__ __align__(16) __bf16 scslab[(KS_SC > 0) ? 4096 : 8];

    const int t = threadIdx.x;
    const int wv = t >> 6, l = t & 63;
    const int wco = wv >> 1, wp = wv & 1;
    const int lrow = l & 15, quad = l >> 4;
    const int pbase = blockIdx.x * 64;
    const int n = pbase >> 8;
    const int rbase = pbase & 255;           // 4-row band within 16x16 image
    const int h2_0 = rbase >> 4;
    const int hb = STRIDE * h2_0 - 1;        // slab h origin in input coords

    // ---- stage main slab (once) ----
    for (int c = t; c < NCH; c += 256) {
        int sub = c & (CPC - 1);
        int cell = c / CPC;
        int w = cell % SLAB_W;
        int h = cell / SLAB_W;
        int hi = hb + h, wi = w - 1;
        uint4 v = {0u, 0u, 0u, 0u};
        if ((unsigned)hi < (unsigned)HIN && (unsigned)wi < (unsigned)HIN)
            v = *(const uint4*)(act + ((size_t)(n * HIN + hi) * HIN + wi) * CIN + sub * 16);
        int key = (w >> (STRIDE - 1)) & (CPC - 1);
        *(uint4*)(slab + cell * CIN + ((sub ^ key) * 16)) = v;
    }
    if constexpr (KS_SC > 0) {
        char* scb = (char*)scslab;
        for (int c = t; c < 512; c += 256) {
            int sub = c & 7, cell = c >> 3;
            int w2 = cell & 15, h2l = cell >> 4;
            uint4 v = *(const uint4*)(actsc +
                ((size_t)(n * 16 + h2_0 + h2l) * 16 + w2) * 64 + sub * 8);
            *(uint4*)(scb + cell * 128 + ((sub * 16) ^ ((w2 & 7) << 4))) = v;
        }
    }
    __syncthreads();                         // slab ready; read-only hereafter

    constexpr int CPS64 = CIN / 64;          // K64-steps per (kh,kw)
    i32x4 acc[4][2] = {};

#pragma unroll
    for (int s = 0; s < KS_MAIN; ++s) {
        const int khw = s / CPS64;           // compile-time after unroll
        const int cis = s % CPS64;
        const int kh = khw / 3, kw = khw % 3;
        i32x4 af[4];
#pragma unroll
        for (int i = 0; i < 4; ++i)
            af[i] = *(const i32x4*)(wqi +
                ((size_t)(s * 128 + wco * 64 + i * 16 + lrow) * 64 + quad * 16));
        i32x4 bfr[2];
#pragma unroll
        for (int j = 0; j < 2; ++j) {
            int sh = STRIDE * (wp * 2 + j) + kh;
            int sw = STRIDE * lrow + kw;
            int chunk = cis * 4 + quad;
            int key = (sw >> (STRIDE - 1)) & (CPC - 1);
            bfr[j] = *(const i32x4*)(slab + (sh * SLAB_W + sw) * CIN + ((chunk ^ key) * 16));
        }
#pragma unroll
        for (int i = 0; i < 4; ++i)
#pragma unroll
            for (int j = 0; j < 2; ++j)
                acc[i][j] = __builtin_amdgcn_mfma_i32_16x16x64_i8(af[i], bfr[j], acc[i][j], 0, 0, 0);
    }

    // ---- shortcut tail (bf16, separate f32 acc) ----
    f32x4 accF[4][2] = {};
    if constexpr (KS_SC > 0) {
        char* scb = (char*)scslab;
#pragma unroll
        for (int s = 0; s < KS_SC; ++s) {
            bf16x8 af[4], bfr[2];
#pragma unroll
            for (int i = 0; i < 4; ++i)
                af[i] = *(const bf16x8*)(wsc + (size_t)s * 4096 +
                    ((wco * 64 + i * 16 + lrow) * 32 + quad * 8));
#pragma unroll
            for (int j = 0; j < 2; ++j) {
                int pl = wp * 32 + j * 16 + lrow;
                int cib = s * 64 + quad * 16;
                bfr[j] = *(const bf16x8*)(scb + pl * 128 + (cib ^ ((lrow & 7) << 4)));
            }
#pragma unroll
            for (int i = 0; i < 4; ++i)
#pragma unroll
                for (int j = 0; j < 2; ++j)
                    accF[i][j] = __builtin_amdgcn_mfma_f32_16x16x32_bf16(af[i], bfr[j], accF[i][j], 0, 0, 0);
        }
    }

    // epilogue: C/D layout col=lane&15 (pos), row=(lane>>4)*4+reg (co)
#pragma unroll
    for (int i = 0; i < 4; ++i) {
        const int co0 = wco * 64 + i * 16 + quad * 4;
        float s2v[4], h2v[4];
        if constexpr (MODE == 0) {
#pragma unroll
            for (int r = 0; r < 4; ++r) {
                s2v[r] = sc2[co0 + r] * (1.f / 225.f);
                h2v[r] = sh2[co0 + r];
            }
        }
#pragma unroll
        for (int j = 0; j < 2; ++j) {
            const int rr = rbase + wp * 32 + j * 16 + lrow;
            if constexpr (MODE == 0) {
                unsigned u = 0;
#pragma unroll
                for (int r = 0; r < 4; ++r) {
                    float v = (float)acc[i][j][r] * s2v[r] + h2v[r];
                    int q = (int)rintf(fminf(fmaxf(v, 0.f), 1.f) * 15.f);
                    u |= (unsigned)q << (8 * r);
                }
                *(unsigned*)(a2out + ((size_t)n * 256 + rr) * 128 + co0) = u;
            } else {
#pragma unroll
                for (int r = 0; r < 4; ++r)
                    dout[((size_t)n * 128 + co0 + r) * 256 + rr] =
                        (float)acc[i][j][r] * (1.f / 225.f) + accF[i][j][r];
            }
        }
    }
}

extern "C" void kernel_launch(void* const* d_in, const int* in_sizes, int n_in,
                              void* d_out, int out_size, void* d_ws, size_t ws_size,
                              hipStream_t stream) {
    const float* x   = (const float*)d_in[0];
    const float* w1  = (const float*)d_in[1];
    const float* w2  = (const float*)d_in[2];
    const float* wsw = (const float*)d_in[3];
    const float* g1  = (const float*)d_in[4];
    const float* b1  = (const float*)d_in[5];
    const float* m1  = (const float*)d_in[6];
    const float* v1  = (const float*)d_in[7];
    const float* g2  = (const float*)d_in[8];
    const float* b2  = (const float*)d_in[9];
    const float* m2  = (const float*)d_in[10];
    const float* v2  = (const float*)d_in[11];
    const float* gs  = (const float*)d_in[12];
    const float* bs  = (const float*)d_in[13];
    const float* ms  = (const float*)d_in[14];
    const float* vs  = (const float*)d_in[15];
    float* out = (float*)d_out;
    char* ws = (char*)d_ws;

    // ws layout (bytes), total ~33.8 MB
    signed char* a1   = (signed char*)(ws);                 // 16 MiB i8
    signed char* a2   = (signed char*)(ws + 16777216);      // 8 MiB i8
    __bf16*      asc  = (__bf16*)(ws + 25165824);           // 8 MiB bf16
    signed char* w1qi = (signed char*)(ws + 33554432);      // 73,728 i8
    signed char* w2qi = (signed char*)(ws + 33628160);      // 147,456 i8
    __bf16*      wsq  = (__bf16*)(ws + 33775616);           // 8,192 bf16
    float*       bnp  = (float*)(ws + 33792000);            // 512 floats
    float*       wmax = (float*)(ws + 33794048);            // 2 floats

    k_init<<<1, 64, 0, stream>>>(wmax);
    k_wmax<<<32, 256, 0, stream>>>(w1, w2, wmax);
    k_bnprep<<<1, 128, 0, stream>>>(g1, b1, m1, v1, g2, b2, m2, v2, gs, bs, ms, vs, bnp);
    k_wq_i8<64><<<288, 256, 0, stream>>>(w1, w1qi, wmax, 73728);
    k_wq_i8<128><<<576, 256, 0, stream>>>(w2, w2qi, wmax + 1, 147456);
    k_wq_bf<<<32, 256, 0, stream>>>(wsw, wsq, 8192);
    k_a1<<<8192, 256, 0, stream>>>(x, bnp, a1, asc);
    // conv1: 3x3 stride 2 pad 1 on a1 (9 K64-steps); epilogue bn2+actq4 -> a2
    conv_mfma<64, 9, 0, 2, 32, 0><<<1024, 256, 0, stream>>>(
        a1, nullptr, w1qi, nullptr, bnp + 256, bnp + 384, a2, nullptr);
    // conv2: 3x3 stride 1 pad 1 on a2 (18 K64-steps) + bf16 shortcut tail -> out
    conv_mfma<128, 18, 2, 1, 16, 1><<<1024, 256, 0, stream>>>(
        a2, asc, w2qi, wsq, nullptr, nullptr, nullptr, out);
}

// Round 10
// 78.746 us; speedup vs baseline: 1.4700x; 1.0889x over previous
//
#include <hip/hip_runtime.h>
#include <hip/hip_bf16.h>

// Wide_BasicBlock_Q: DoReFa-quantized residual block on MI355X (gfx950).
// Round 9: occupancy + chain-shrink on the i8 conv structure.
//   - conv blocks: 512 threads / 8 waves, wave tile 32co x 32pos (acc 2x2),
//     __launch_bounds__(512,6) -> target 24 waves/CU (was 16)
//   - explicit depth-1 weight prefetch (static ping-pong, unrolled K-loop)
//   - shortcut tail accumulates INTO converted main acc (C-in), no accF
//   - prep diet: no k_init/atomics (plain partial-max stores), fused k_wq_all,
//     quant scale 15/(2 tanh(max|w|)) precomputed in k_bnprep

typedef __bf16 bf16x8 __attribute__((ext_vector_type(8)));
typedef float f32x4 __attribute__((ext_vector_type(4)));
typedef int i32x4 __attribute__((ext_vector_type(4)));

#define EPSV 1e-5f

// per-block partial max|w| -> wpart[b] (plain store, deterministic)
__global__ __launch_bounds__(256) void k_wmax(const float* __restrict__ w1,
                                              const float* __restrict__ w2,
                                              float* __restrict__ wpart) {
    int sel = blockIdx.x >> 4;                 // 0: w1, 1: w2
    const float* src = sel ? w2 : w1;
    int cnt = sel ? 128 * 128 * 9 : 128 * 64 * 9;
    float m = 0.f;
    for (int i = (blockIdx.x & 15) * 256 + threadIdx.x; i < cnt; i += 16 * 256)
        m = fmaxf(m, fabsf(src[i]));
#pragma unroll
    for (int off = 32; off > 0; off >>= 1)
        m = fmaxf(m, __shfl_down(m, off));
    __shared__ float red[4];
    if ((threadIdx.x & 63) == 0) red[threadIdx.x >> 6] = m;
    __syncthreads();
    if (threadIdx.x == 0)
        wpart[blockIdx.x] = fmaxf(fmaxf(red[0], red[1]), fmaxf(red[2], red[3]));
}

// bnp layout (floats): [0:64)=sc1 [64:128)=sh1 [128:192)=scs [192:256)=shs
// [256:384)=sc2 [384:512)=sh2 [512]=c1 [513]=c2  (c = 15/(2 tanh(max|w|)))
__global__ void k_bnprep(const float* g1, const float* b1, const float* m1, const float* v1,
                         const float* g2, const float* b2, const float* m2, const float* v2,
                         const float* gs, const float* bs, const float* ms, const float* vs,
                         const float* __restrict__ wpart, float* bnp) {
    int c = threadIdx.x;  // blockDim = 128
    if (c < 64) {
        float s = g1[c] * rsqrtf(v1[c] + EPSV);
        bnp[c] = s;          bnp[64 + c] = b1[c] - m1[c] * s;
        float s2 = gs[c] * rsqrtf(vs[c] + EPSV);
        bnp[128 + c] = s2;   bnp[192 + c] = bs[c] - ms[c] * s2;
    }
    float s = g2[c] * rsqrtf(v2[c] + EPSV);
    bnp[256 + c] = s;        bnp[384 + c] = b2[c] - m2[c] * s;
    if (c < 2) {
        float m = 0.f;
#pragma unroll
        for (int i = 0; i < 16; ++i) m = fmaxf(m, wpart[c * 16 + i]);
        bnp[512 + c] = 15.f / (2.f * tanhf(m));
    }
}

// All weight packs in one dispatch (grid 896):
//  b<288 : w1 -> i8 [(s*128+co)*64+kk], k=s*64+kk, k-order khw*64+ci
//  b<864 : w2 -> i8 same with CIN=128
//  else  : wsw -> bf16 [(s*128+co)*32+kk] (1x1: k=ci), unquantized
__global__ __launch_bounds__(256) void k_wq_all(
        const float* __restrict__ w1, const float* __restrict__ w2,
        const float* __restrict__ wsw,
        signed char* __restrict__ w1qi, signed char* __restrict__ w2qi,
        __bf16* __restrict__ wsq, const float* __restrict__ bnp) {
    int b = blockIdx.x, t = threadIdx.x;
    if (b < 864) {
        bool isw1 = b < 288;
        int idx = (isw1 ? b : b - 288) * 256 + t;
        float c = bnp[512 + (isw1 ? 0 : 1)];
        int kk = idx & 63;
        int co = (idx >> 6) & 127;
        int s = idx >> 13;
        int k = s * 64 + kk;
        int khw, ci;
        const float* src;
        if (isw1) { khw = k >> 6; ci = k & 63;  src = w1 + (co * 64 + ci) * 9 + khw; }
        else      { khw = k >> 7; ci = k & 127; src = w2 + (co * 128 + ci) * 9 + khw; }
        int j = (int)rintf(tanhf(*src) * c + 7.5f);
        (isw1 ? w1qi : w2qi)[idx] = (signed char)(2 * j - 15);
    } else {
        int idx = (b - 864) * 256 + t;
        int kk = idx & 31;
        int co = (idx >> 5) & 127;
        int s = idx >> 12;
        wsq[idx] = (__bf16)wsw[co * 64 + s * 32 + kk];
    }
}

// a1 = round(15*actq) ints -> NHWC i8 [256][32][32][64]
// asc = bn_s(x) at even (h,w) -> NHWC bf16 [256][16][16][64]
__global__ __launch_bounds__(256) void k_a1(const float* __restrict__ x,
                                            const float* __restrict__ bnp,
                                            signed char* __restrict__ a1,
                                            __bf16* __restrict__ asc) {
    __shared__ __align__(16) signed char l1[32][80];
    __shared__ __align__(16) __bf16 l2[16][72];
    __shared__ float s1[64], h1[64], ss[64], hs[64];
    int t = threadIdx.x;
    int n = blockIdx.x >> 5, h = blockIdx.x & 31;
    if (t < 64) {
        s1[t] = bnp[t];       h1[t] = bnp[64 + t];
        ss[t] = bnp[128 + t]; hs[t] = bnp[192 + t];
    }
    __syncthreads();
    bool he = (h & 1) == 0;
#pragma unroll
    for (int i = 0; i < 2; ++i) {
        int idx = t + i * 256;          // over (c,w4): c=idx>>3, w0=(idx&7)*4
        int c = idx >> 3, w0 = (idx & 7) * 4;
        float4 xv = *(const float4*)(x + (((size_t)(n * 64 + c) * 32 + h) * 32 + w0));
        float xa[4] = {xv.x, xv.y, xv.z, xv.w};
#pragma unroll
        for (int k = 0; k < 4; ++k) {
            float v = xa[k] * s1[c] + h1[c];
            l1[w0 + k][c] = (signed char)(int)rintf(fminf(fmaxf(v, 0.f), 1.f) * 15.f);
        }
        if (he) {
            l2[w0 >> 1][c]       = (__bf16)(xa[0] * ss[c] + hs[c]);
            l2[(w0 >> 1) + 1][c] = (__bf16)(xa[2] * ss[c] + hs[c]);
        }
    }
    __syncthreads();
    {
        int o = t * 8;                  // over (w,c): w=o>>6, c=o&63
        int w = o >> 6, c = o & 63;
        *(uint2*)(a1 + (((size_t)(n * 32 + h)) * 32 + w) * 64 + c) = *(uint2*)&l1[w][c];
    }
    if (he) {
        int o = t * 4;
        int w2 = o >> 6, c = o & 63;
        *(uint2*)(asc + (((size_t)(n * 16 + (h >> 1))) * 16 + w2) * 64 + c) = *(uint2*)&l2[w2][c];
    }
}

// Implicit-GEMM conv via MFMA i32_16x16x64_i8 — LDS slab, 8-wave blocks.
// Block: 512 thr = 8 waves (4co x 2pos); block tile 128co x 64pos; wave tile
// 32co x 32pos (acc 2x2, 4 MFMA/K64-step). Grid 1024.
// Slab: [3S+3][15S+3][CIN] i8, zero-padded, 16B-chunk XOR swizzle, staged once.
// Weights: 2x 16B reg loads/lane/step, explicit depth-1 prefetch (static
// ping-pong; K-loop fully unrolled). No barriers in the K-loop.
// Shortcut tail (KS_SC>0): bf16 16x16x32 steps accumulate into the CONVERTED
// main acc (C-in), from swizzled asc mini-slab.
// MODE 0: bn2+actq4 -> a2out ints (NHWC i8); MODE 1: dout fp32 NCHW.
template <int CIN, int KS_MAIN, int KS_SC, int STRIDE, int HIN, int MODE>
__global__ __launch_bounds__(512, 6) void conv_mfma(
        const signed char* __restrict__ act, const __bf16* __restrict__ actsc,
        const signed char* __restrict__ wqi, const __bf16* __restrict__ wsc,
        const float* __restrict__ sc2, const float* __restrict__ sh2,
        signed char* __restrict__ a2out, float* __restrict__ dout) {
    constexpr int SLAB_H = 3 * STRIDE + 3;
    constexpr int SLAB_W = 15 * STRIDE + 3;
    constexpr int CPC = CIN / 16;            // 16B chunks per (h,w) cell
    constexpr int NCH = SLAB_H * SLAB_W * CPC;
    __shared__ __align__(16) signed char slab[SLAB_H * SLAB_W * CIN];
    __shared__ __align__(16) __bf16 scslab[(KS_SC > 0) ? 4096 : 8];

    const int t = threadIdx.x;
    const int wv = t >> 6, l = t & 63;
    const int wco = wv >> 1, wp = wv & 1;    // wco 0..3 (32co), wp 0..1 (32pos)
    const int lrow = l & 15, quad = l >> 4;
    const int pbase = blockIdx.x * 64;
    const int n = pbase >> 8;
    const int rbase = pbase & 255;           // 4-row band within 16x16 image
    const int h2_0 = rbase >> 4;
    const int hb = STRIDE * h2_0 - 1;        // slab h origin in input coords

    // ---- stage main slab (once) ----
    for (int c = t; c < NCH; c += 512) {
        int sub = c & (CPC - 1);
        int cell = c / CPC;
        int w = cell % SLAB_W;
        int h = cell / SLAB_W;
        int hi = hb + h, wi = w - 1;
        uint4 v = {0u, 0u, 0u, 0u};
        if ((unsigned)hi < (unsigned)HIN && (unsigned)wi < (unsigned)HIN)
            v = *(const uint4*)(act + ((size_t)(n * HIN + hi) * HIN + wi) * CIN + sub * 16);
        int key = (w >> (STRIDE - 1)) & (CPC - 1);
        *(uint4*)(slab + cell * CIN + ((sub ^ key) * 16)) = v;
    }
    if constexpr (KS_SC > 0) {
        char* scb = (char*)scslab;
        {
            int sub = t & 7, cell = t >> 3;      // 512 chunks, one per thread
            int w2 = cell & 15, h2l = cell >> 4;
            uint4 v = *(const uint4*)(actsc +
                ((size_t)(n * 16 + h2_0 + h2l) * 16 + w2) * 64 + sub * 8);
            *(uint4*)(scb + cell * 128 + ((sub * 16) ^ ((w2 & 7) << 4)));
            *(uint4*)(scb + cell * 128 + ((sub * 16) ^ ((w2 & 7) << 4))) = v;
        }
    }
    __syncthreads();                         // slab ready; read-only hereafter

    constexpr int CPS64 = CIN / 64;          // K64-steps per (kh,kw)
    i32x4 acc[2][2] = {};

    auto loadA = [&](int s, i32x4* dst) {
#pragma unroll
        for (int i = 0; i < 2; ++i)
            dst[i] = *(const i32x4*)(wqi +
                ((size_t)(s * 128 + wco * 32 + i * 16 + lrow) * 64 + quad * 16));
    };
    auto loadB = [&](int s, i32x4* bfr) {
        const int khw = s / CPS64;
        const int cis = s % CPS64;
        const int kh = khw / 3, kw = khw % 3;
#pragma unroll
        for (int j = 0; j < 2; ++j) {
            int sh = STRIDE * (wp * 2 + j) + kh;
            int sw = STRIDE * lrow + kw;
            int chunk = cis * 4 + quad;
            int key = (sw >> (STRIDE - 1)) & (CPC - 1);
            bfr[j] = *(const i32x4*)(slab + (sh * SLAB_W + sw) * CIN + ((chunk ^ key) * 16));
        }
    };

    i32x4 afA[2], afB[2], bfr[2];
    loadA(0, afA);
#pragma unroll
    for (int s = 0; s < KS_MAIN; ++s) {
        i32x4* cur = (s & 1) ? afB : afA;    // static after full unroll
        i32x4* nxt = (s & 1) ? afA : afB;
        if (s + 1 < KS_MAIN) loadA(s + 1, nxt);
        loadB(s, bfr);
#pragma unroll
        for (int i = 0; i < 2; ++i)
#pragma unroll
            for (int j = 0; j < 2; ++j)
                acc[i][j] = __builtin_amdgcn_mfma_i32_16x16x64_i8(cur[i], bfr[j], acc[i][j], 0, 0, 0);
    }

    // convert exact int acc -> f32/225 (C-in for shortcut tail)
    f32x4 accM[2][2];
#pragma unroll
    for (int i = 0; i < 2; ++i)
#pragma unroll
        for (int j = 0; j < 2; ++j)
#pragma unroll
            for (int r = 0; r < 4; ++r)
                accM[i][j][r] = (float)acc[i][j][r] * (1.f / 225.f);

    if constexpr (KS_SC > 0) {
        char* scb = (char*)scslab;
#pragma unroll
        for (int s = 0; s < KS_SC; ++s) {
            bf16x8 af[2], bb[2];
#pragma unroll
            for (int i = 0; i < 2; ++i)
                af[i] = *(const bf16x8*)(wsc + (size_t)s * 4096 +
                    ((wco * 32 + i * 16 + lrow) * 32 + quad * 8));
#pragma unroll
            for (int j = 0; j < 2; ++j) {
                int pl = wp * 32 + j * 16 + lrow;
                int cib = s * 64 + quad * 16;
                bb[j] = *(const bf16x8*)(scb + pl * 128 + (cib ^ ((lrow & 7) << 4)));
            }
#pragma unroll
            for (int i = 0; i < 2; ++i)
#pragma unroll
                for (int j = 0; j < 2; ++j)
                    accM[i][j] = __builtin_amdgcn_mfma_f32_16x16x32_bf16(af[i], bb[j], accM[i][j], 0, 0, 0);
        }
    }

    // epilogue: C/D layout col=lane&15 (pos), row=(lane>>4)*4+reg (co)
#pragma unroll
    for (int i = 0; i < 2; ++i) {
        const int co0 = wco * 32 + i * 16 + quad * 4;
        float s2v[4], h2v[4];
        if constexpr (MODE == 0) {
#pragma unroll
            for (int r = 0; r < 4; ++r) {
                s2v[r] = sc2[co0 + r] * (1.f / 225.f);
                h2v[r] = sh2[co0 + r];
            }
        }
#pragma unroll
        for (int j = 0; j < 2; ++j) {
            const int rr = rbase + wp * 32 + j * 16 + lrow;
            if constexpr (MODE == 0) {
                unsigned u = 0;
#pragma unroll
                for (int r = 0; r < 4; ++r) {
                    float v = (float)acc[i][j][r] * s2v[r] + h2v[r];
                    int q = (int)rintf(fminf(fmaxf(v, 0.f), 1.f) * 15.f);
                    u |= (unsigned)q << (8 * r);
                }
                *(unsigned*)(a2out + ((size_t)n * 256 + rr) * 128 + co0) = u;
            } else {
#pragma unroll
                for (int r = 0; r < 4; ++r)
                    dout[((size_t)n * 128 + co0 + r) * 256 + rr] = accM[i][j][r];
            }
        }
    }
}

extern "C" void kernel_launch(void* const* d_in, const int* in_sizes, int n_in,
                              void* d_out, int out_size, void* d_ws, size_t ws_size,
                              hipStream_t stream) {
    const float* x   = (const float*)d_in[0];
    const float* w1  = (const float*)d_in[1];
    const float* w2  = (const float*)d_in[2];
    const float* wsw = (const float*)d_in[3];
    const float* g1  = (const float*)d_in[4];
    const float* b1  = (const float*)d_in[5];
    const float* m1  = (const float*)d_in[6];
    const float* v1  = (const float*)d_in[7];
    const float* g2  = (const float*)d_in[8];
    const float* b2  = (const float*)d_in[9];
    const float* m2  = (const float*)d_in[10];
    const float* v2  = (const float*)d_in[11];
    const float* gs  = (const float*)d_in[12];
    const float* bs  = (const float*)d_in[13];
    const float* ms  = (const float*)d_in[14];
    const float* vs  = (const float*)d_in[15];
    float* out = (float*)d_out;
    char* ws = (char*)d_ws;

    // ws layout (bytes), total ~33.8 MB
    signed char* a1   = (signed char*)(ws);                 // 16 MiB i8
    signed char* a2   = (signed char*)(ws + 16777216);      // 8 MiB i8
    __bf16*      asc  = (__bf16*)(ws + 25165824);           // 8 MiB bf16
    signed char* w1qi = (signed char*)(ws + 33554432);      // 73,728 i8
    signed char* w2qi = (signed char*)(ws + 33628160);      // 147,456 i8
    __bf16*      wsq  = (__bf16*)(ws + 33775616);           // 8,192 bf16
    float*       bnp  = (float*)(ws + 33792000);            // 514 floats
    float*       wprt = (float*)(ws + 33794560);            // 32 floats

    k_wmax<<<32, 256, 0, stream>>>(w1, w2, wprt);
    k_bnprep<<<1, 128, 0, stream>>>(g1, b1, m1, v1, g2, b2, m2, v2,
                                    gs, bs, ms, vs, wprt, bnp);
    k_wq_all<<<896, 256, 0, stream>>>(w1, w2, wsw, w1qi, w2qi, wsq, bnp);
    k_a1<<<8192, 256, 0, stream>>>(x, bnp, a1, asc);
    // conv1: 3x3 stride 2 pad 1 on a1 (9 K64-steps); epilogue bn2+actq4 -> a2
    conv_mfma<64, 9, 0, 2, 32, 0><<<1024, 512, 0, stream>>>(
        a1, nullptr, w1qi, nullptr, bnp + 256, bnp + 384, a2, nullptr);
    // conv2: 3x3 stride 1 pad 1 on a2 (18 K64-steps) + bf16 shortcut tail -> out
    conv_mfma<128, 18, 2, 1, 16, 1><<<1024, 512, 0, stream>>>(
        a2, asc, w2qi, wsq, nullptr, nullptr, nullptr, out);
}

// Round 11
// 61.359 us; speedup vs baseline: 1.8866x; 1.2834x over previous
//
#include <hip/hip_runtime.h>
#include <hip/hip_bf16.h>

// Wide_BasicBlock_Q: DoReFa-quantized residual block on MI355X (gfx950).
// Round 10: mega-kernel — one block per image, all intermediates in LDS.
//   P1: stream x (f32 NCHW) -> bn1+actq -> i8 slab[34][34][64] (zero-padded,
//       chunk-XOR swizzled) + bn_s -> bf16 asc[16][16][64]        (LDS)
//   P2: conv1 (i8 MFMA 16x16x64, weights global->reg) -> bn2+actq -> i8
//       a2p[18][18][128] zero-padded swizzled                     (LDS)
//   P3: conv2 (18 i8 K64-steps from a2p) + bf16 shortcut (2 steps from asc)
//       -> fp32 NCHW out
// HBM: x 67MB + out 33.5MB + weights only. a1/a2/asc never touch HBM.
// 1024 thr / 16 waves / ~145KB LDS -> 1 block/CU, 4 waves/SIMD.

typedef __bf16 bf16x8 __attribute__((ext_vector_type(8)));
typedef float f32x4 __attribute__((ext_vector_type(4)));
typedef int i32x4 __attribute__((ext_vector_type(4)));

#define EPSV 1e-5f

// per-block partial max|w| -> wpart[b] (plain store, deterministic)
__global__ __launch_bounds__(256) void k_wmax(const float* __restrict__ w1,
                                              const float* __restrict__ w2,
                                              float* __restrict__ wpart) {
    int sel = blockIdx.x >> 4;                 // 0: w1, 1: w2
    const float* src = sel ? w2 : w1;
    int cnt = sel ? 128 * 128 * 9 : 128 * 64 * 9;
    float m = 0.f;
    for (int i = (blockIdx.x & 15) * 256 + threadIdx.x; i < cnt; i += 16 * 256)
        m = fmaxf(m, fabsf(src[i]));
#pragma unroll
    for (int off = 32; off > 0; off >>= 1)
        m = fmaxf(m, __shfl_down(m, off));
    __shared__ float red[4];
    if ((threadIdx.x & 63) == 0) red[threadIdx.x >> 6] = m;
    __syncthreads();
    if (threadIdx.x == 0)
        wpart[blockIdx.x] = fmaxf(fmaxf(red[0], red[1]), fmaxf(red[2], red[3]));
}

// bnp layout (floats): [0:64)=sc1 [64:128)=sh1 [128:192)=scs [192:256)=shs
// [256:384)=sc2 [384:512)=sh2 [512]=c1 [513]=c2  (c = 15/(2 tanh(max|w|)))
__global__ void k_bnprep(const float* g1, const float* b1, const float* m1, const float* v1,
                         const float* g2, const float* b2, const float* m2, const float* v2,
                         const float* gs, const float* bs, const float* ms, const float* vs,
                         const float* __restrict__ wpart, float* bnp) {
    int c = threadIdx.x;  // blockDim = 128
    if (c < 64) {
        float s = g1[c] * rsqrtf(v1[c] + EPSV);
        bnp[c] = s;          bnp[64 + c] = b1[c] - m1[c] * s;
        float s2 = gs[c] * rsqrtf(vs[c] + EPSV);
        bnp[128 + c] = s2;   bnp[192 + c] = bs[c] - ms[c] * s2;
    }
    float s = g2[c] * rsqrtf(v2[c] + EPSV);
    bnp[256 + c] = s;        bnp[384 + c] = b2[c] - m2[c] * s;
    if (c < 2) {
        float m = 0.f;
#pragma unroll
        for (int i = 0; i < 16; ++i) m = fmaxf(m, wpart[c * 16 + i]);
        bnp[512 + c] = 15.f / (2.f * tanhf(m));
    }
}

// All weight packs in one dispatch (grid 896):
//  b<288 : w1 -> i8 [(s*128+co)*64+kk], k=s*64+kk, k-order khw*64+ci
//  b<864 : w2 -> i8 same with CIN=128
//  else  : wsw -> bf16 [(s*128+co)*32+kk] (1x1: k=ci), unquantized
__global__ __launch_bounds__(256) void k_wq_all(
        const float* __restrict__ w1, const float* __restrict__ w2,
        const float* __restrict__ wsw,
        signed char* __restrict__ w1qi, signed char* __restrict__ w2qi,
        __bf16* __restrict__ wsq, const float* __restrict__ bnp) {
    int b = blockIdx.x, t = threadIdx.x;
    if (b < 864) {
        bool isw1 = b < 288;
        int idx = (isw1 ? b : b - 288) * 256 + t;
        float c = bnp[512 + (isw1 ? 0 : 1)];
        int kk = idx & 63;
        int co = (idx >> 6) & 127;
        int s = idx >> 13;
        int k = s * 64 + kk;
        int khw, ci;
        const float* src;
        if (isw1) { khw = k >> 6; ci = k & 63;  src = w1 + (co * 64 + ci) * 9 + khw; }
        else      { khw = k >> 7; ci = k & 127; src = w2 + (co * 128 + ci) * 9 + khw; }
        int j = (int)rintf(tanhf(*src) * c + 7.5f);
        (isw1 ? w1qi : w2qi)[idx] = (signed char)(2 * j - 15);
    } else {
        int idx = (b - 864) * 256 + t;
        int kk = idx & 31;
        int co = (idx >> 5) & 127;
        int s = idx >> 12;
        wsq[idx] = (__bf16)wsw[co * 64 + s * 32 + kk];
    }
}

// ---- mega kernel: one image per block ----
__global__ __launch_bounds__(1024, 4) void k_mega(
        const float* __restrict__ x,
        const signed char* __restrict__ w1qi,
        const signed char* __restrict__ w2qi,
        const __bf16* __restrict__ wsq,
        const float* __restrict__ bnp,
        float* __restrict__ out) {
    // LDS: slab 34*34*64 = 73984 | a2p 18*18*128 = 41472 | asc 256*128 = 32768
    __shared__ __align__(16) char lds_all[73984 + 41472 + 32768];
    signed char* slab = (signed char*)lds_all;
    signed char* a2p  = (signed char*)(lds_all + 73984);
    char*        ascb = lds_all + 73984 + 41472;

    const int t = threadIdx.x;
    const int n = blockIdx.x;
    const int wv = t >> 6, l = t & 63;
    const int lrow = l & 15, quad = l >> 4;

    // ---- P1a: zero borders ----
    if (t < 528) {                       // slab: 132 border cells x 4 chunks
        int ci_ = t >> 2, sub = t & 3;
        int cell;
        if (ci_ < 34)      cell = ci_;                    // ph = 0
        else if (ci_ < 68) cell = 33 * 34 + (ci_ - 34);   // ph = 33
        else { int k = ci_ - 68; cell = (1 + (k >> 1)) * 34 + (k & 1) * 33; }
        *(uint4*)(slab + cell * 64 + sub * 16) = uint4{0u, 0u, 0u, 0u};
    }
    if (t < 544) {                       // a2p: 68 border cells x 8 chunks
        int ci_ = t >> 3, sub = t & 7;
        int cell;
        if (ci_ < 18)      cell = ci_;                    // ph = 0
        else if (ci_ < 36) cell = 17 * 18 + (ci_ - 18);   // ph = 17
        else { int k = ci_ - 36; cell = (1 + (k >> 1)) * 18 + (k & 1) * 17; }
        *(uint4*)(a2p + cell * 128 + sub * 16) = uint4{0u, 0u, 0u, 0u};
    }

    // ---- P1b: x -> bn1+actq -> slab; bn_s -> asc ----
#pragma unroll
    for (int it = 0; it < 4; ++it) {
        int u = t + it * 1024;           // 4096 units: (cq 0..15) x (wq 0..255)
        int wq = u & 255;
        int cq = u >> 8;
        int p0 = wq * 4;
        int h = p0 >> 5, w0 = p0 & 31;
        int c0 = cq * 4;
        float4 s1 = *(const float4*)(bnp + c0);
        float4 h1 = *(const float4*)(bnp + 64 + c0);
        float4 ssv = *(const float4*)(bnp + 128 + c0);
        float4 hsv = *(const float4*)(bnp + 192 + c0);
        const float* s1p = (const float*)&s1;
        const float* h1p = (const float*)&h1;
        const float* ssp = (const float*)&ssv;
        const float* hsp = (const float*)&hsv;
        float4 xr[4];
#pragma unroll
        for (int j = 0; j < 4; ++j)
            xr[j] = *(const float4*)(x + ((size_t)(n * 64 + c0 + j)) * 1024 + p0);
#pragma unroll
        for (int k = 0; k < 4; ++k) {
            unsigned u32 = 0;
#pragma unroll
            for (int j = 0; j < 4; ++j) {
                float xv = ((const float*)&xr[j])[k];
                float v = xv * s1p[j] + h1p[j];
                int q = (int)rintf(fminf(fmaxf(v, 0.f), 1.f) * 15.f);
                u32 |= (unsigned)q << (8 * j);
            }
            int pw = w0 + k + 1, ph = h + 1;
            int cell = ph * 34 + pw;
            int key = (pw >> 1) & 3;
            *(unsigned*)(slab + cell * 64 + (((cq >> 2) ^ key) * 16) + (cq & 3) * 4) = u32;
        }
        if ((h & 1) == 0) {
#pragma unroll
            for (int k = 0; k < 4; k += 2) {
                int w = w0 + k;
                __bf16 bv[4];
#pragma unroll
                for (int j = 0; j < 4; ++j) {
                    float xv = ((const float*)&xr[j])[k];
                    bv[j] = (__bf16)(xv * ssp[j] + hsp[j]);
                }
                int cell = (h >> 1) * 16 + (w >> 1);
                int key = (w >> 1) & 7;
                *(uint2*)(ascb + cell * 128 + (((cq >> 1) ^ key) * 16) + (cq & 1) * 8) =
                    *(uint2*)bv;
            }
        }
    }
    __syncthreads();

    const int wco = wv & 1;              // 2 co-tiles of 64
    const int wpos = wv >> 1;            // 8 pos-tiles (2 h2-rows x 16 w2)

    // ---- P2: conv1 (3x3 s2 p1, CIN=64, 9 K64-steps) -> a2p ----
    {
        i32x4 acc1[4][2] = {};
#pragma unroll
        for (int s = 0; s < 9; ++s) {
            const int kh = s / 3, kw = s % 3;
            i32x4 af[4];
#pragma unroll
            for (int i = 0; i < 4; ++i)
                af[i] = *(const i32x4*)(w1qi +
                    ((s * 128 + wco * 64 + i * 16 + lrow) * 64 + quad * 16));
            i32x4 bf[2];
#pragma unroll
            for (int j = 0; j < 2; ++j) {
                int h2 = wpos * 2 + j;
                int ph = 2 * h2 + kh;
                int pw = 2 * lrow + kw;
                int key = (pw >> 1) & 3;
                bf[j] = *(const i32x4*)(slab + (ph * 34 + pw) * 64 + ((quad ^ key) * 16));
            }
#pragma unroll
            for (int i = 0; i < 4; ++i)
#pragma unroll
                for (int j = 0; j < 2; ++j)
                    acc1[i][j] = __builtin_amdgcn_mfma_i32_16x16x64_i8(af[i], bf[j], acc1[i][j], 0, 0, 0);
        }
        // epilogue: bn2+actq -> a2p ints
#pragma unroll
        for (int i = 0; i < 4; ++i) {
            const int co0 = wco * 64 + i * 16 + quad * 4;
            float4 s2 = *(const float4*)(bnp + 256 + co0);
            float4 h2f = *(const float4*)(bnp + 384 + co0);
            const float* s2p = (const float*)&s2;
            const float* h2p = (const float*)&h2f;
#pragma unroll
            for (int j = 0; j < 2; ++j) {
                int h2 = wpos * 2 + j, w2 = lrow;
                unsigned u32 = 0;
#pragma unroll
                for (int r = 0; r < 4; ++r) {
                    float v = (float)acc1[i][j][r] * (s2p[r] * (1.f / 225.f)) + h2p[r];
                    int q = (int)rintf(fminf(fmaxf(v, 0.f), 1.f) * 15.f);
                    u32 |= (unsigned)q << (8 * r);
                }
                int cell = (h2 + 1) * 18 + (w2 + 1);
                int key = (w2 + 1) & 7;
                *(unsigned*)(a2p + cell * 128 + ((((co0 >> 4) ^ key)) * 16) + (co0 & 15)) = u32;
            }
        }
    }
    __syncthreads();

    // ---- P3: conv2 (3x3 s1 p1, CIN=128, 18 K64-steps) + bf16 shortcut ----
    {
        i32x4 acc2[4][2] = {};
#pragma unroll
        for (int s = 0; s < 18; ++s) {
            const int khw = s >> 1, cis = s & 1;
            const int kh = khw / 3, kw = khw % 3;
            i32x4 af[4];
#pragma unroll
            for (int i = 0; i < 4; ++i)
                af[i] = *(const i32x4*)(w2qi +
                    ((s * 128 + wco * 64 + i * 16 + lrow) * 64 + quad * 16));
            i32x4 bf[2];
#pragma unroll
            for (int j = 0; j < 2; ++j) {
                int h2 = wpos * 2 + j;
                int ph = h2 + kh, pw = lrow + kw;
                int chunk = cis * 4 + quad;
                int key = pw & 7;
                bf[j] = *(const i32x4*)(a2p + (ph * 18 + pw) * 128 + ((chunk ^ key) * 16));
            }
#pragma unroll
            for (int i = 0; i < 4; ++i)
#pragma unroll
                for (int j = 0; j < 2; ++j)
                    acc2[i][j] = __builtin_amdgcn_mfma_i32_16x16x64_i8(af[i], bf[j], acc2[i][j], 0, 0, 0);
        }
        f32x4 accM[4][2];
#pragma unroll
        for (int i = 0; i < 4; ++i)
#pragma unroll
            for (int j = 0; j < 2; ++j)
#pragma unroll
                for (int r = 0; r < 4; ++r)
                    accM[i][j][r] = (float)acc2[i][j][r] * (1.f / 225.f);
        // shortcut: 2 bf16 K32-steps from asc, C-in = accM
#pragma unroll
        for (int s = 0; s < 2; ++s) {
            bf16x8 af[4], bb[2];
#pragma unroll
            for (int i = 0; i < 4; ++i)
                af[i] = *(const bf16x8*)(wsq + (size_t)s * 4096 +
                    ((wco * 64 + i * 16 + lrow) * 32 + quad * 8));
#pragma unroll
            for (int j = 0; j < 2; ++j) {
                int h2 = wpos * 2 + j, w2 = lrow;
                int cell = h2 * 16 + w2;
                int sub = s * 4 + quad;
                bb[j] = *(const bf16x8*)(ascb + cell * 128 + ((sub ^ (w2 & 7)) * 16));
            }
#pragma unroll
            for (int i = 0; i < 4; ++i)
#pragma unroll
                for (int j = 0; j < 2; ++j)
                    accM[i][j] = __builtin_amdgcn_mfma_f32_16x16x32_bf16(af[i], bb[j], accM[i][j], 0, 0, 0);
        }
        // store out fp32 NCHW
#pragma unroll
        for (int i = 0; i < 4; ++i) {
            const int co0 = wco * 64 + i * 16 + quad * 4;
#pragma unroll
            for (int j = 0; j < 2; ++j) {
                int pos = (wpos * 2 + j) * 16 + lrow;
#pragma unroll
                for (int r = 0; r < 4; ++r)
                    out[((size_t)n * 128 + co0 + r) * 256 + pos] = accM[i][j][r];
            }
        }
    }
}

extern "C" void kernel_launch(void* const* d_in, const int* in_sizes, int n_in,
                              void* d_out, int out_size, void* d_ws, size_t ws_size,
                              hipStream_t stream) {
    const float* x   = (const float*)d_in[0];
    const float* w1  = (const float*)d_in[1];
    const float* w2  = (const float*)d_in[2];
    const float* wsw = (const float*)d_in[3];
    const float* g1  = (const float*)d_in[4];
    const float* b1  = (const float*)d_in[5];
    const float* m1  = (const float*)d_in[6];
    const float* v1  = (const float*)d_in[7];
    const float* g2  = (const float*)d_in[8];
    const float* b2  = (const float*)d_in[9];
    const float* m2  = (const float*)d_in[10];
    const float* v2  = (const float*)d_in[11];
    const float* gs  = (const float*)d_in[12];
    const float* bs  = (const float*)d_in[13];
    const float* ms  = (const float*)d_in[14];
    const float* vs  = (const float*)d_in[15];
    float* out = (float*)d_out;
    char* ws = (char*)d_ws;

    // ws layout (bytes), ~256 KB total
    signed char* w1qi = (signed char*)(ws);                 // 73,728 i8
    signed char* w2qi = (signed char*)(ws + 73728);         // 147,456 i8
    __bf16*      wsq  = (__bf16*)(ws + 221184);             // 8,192 bf16
    float*       bnp  = (float*)(ws + 237568);              // 514 floats
    float*       wprt = (float*)(ws + 240128);              // 32 floats

    k_wmax<<<32, 256, 0, stream>>>(w1, w2, wprt);
    k_bnprep<<<1, 128, 0, stream>>>(g1, b1, m1, v1, g2, b2, m2, v2,
                                    gs, bs, ms, vs, wprt, bnp);
    k_wq_all<<<896, 256, 0, stream>>>(w1, w2, wsw, w1qi, w2qi, wsq, bnp);
    k_mega<<<256, 1024, 0, stream>>>(x, w1qi, w2qi, wsq, bnp, out);
}

// Round 12
// 61.253 us; speedup vs baseline: 1.8899x; 1.0017x over previous
//
#include <hip/hip_runtime.h>
#include <hip/hip_bf16.h>

// Wide_BasicBlock_Q: DoReFa-quantized residual block on MI355X (gfx950).
// Round 10: mega-kernel — one block per image, all intermediates in LDS.
//   P1: stream x (f32 NCHW) -> bn1+actq -> i8 slab[34][34][64] (zero-padded,
//       chunk-XOR swizzled) + bn_s -> bf16 asc[16][16][64]        (LDS)
//   P2: conv1 (i8 MFMA 16x16x64, weights global->reg) -> bn2+actq -> i8
//       a2p[18][18][128] zero-padded swizzled                     (LDS)
//   P3: conv2 (18 i8 K64-steps from a2p) + bf16 shortcut (2 steps from asc)
//       -> fp32 NCHW out
// HBM: x 67MB + out 33.5MB + weights only. a1/a2/asc never touch HBM.
// 1024 thr / 16 waves / ~145KB LDS -> 1 block/CU, 4 waves/SIMD.

typedef __bf16 bf16x8 __attribute__((ext_vector_type(8)));
typedef float f32x4 __attribute__((ext_vector_type(4)));
typedef int i32x4 __attribute__((ext_vector_type(4)));

#define EPSV 1e-5f

// per-block partial max|w| -> wpart[b] (plain store, deterministic)
__global__ __launch_bounds__(256) void k_wmax(const float* __restrict__ w1,
                                              const float* __restrict__ w2,
                                              float* __restrict__ wpart) {
    int sel = blockIdx.x >> 4;                 // 0: w1, 1: w2
    const float* src = sel ? w2 : w1;
    int cnt = sel ? 128 * 128 * 9 : 128 * 64 * 9;
    float m = 0.f;
    for (int i = (blockIdx.x & 15) * 256 + threadIdx.x; i < cnt; i += 16 * 256)
        m = fmaxf(m, fabsf(src[i]));
#pragma unroll
    for (int off = 32; off > 0; off >>= 1)
        m = fmaxf(m, __shfl_down(m, off));
    __shared__ float red[4];
    if ((threadIdx.x & 63) == 0) red[threadIdx.x >> 6] = m;
    __syncthreads();
    if (threadIdx.x == 0)
        wpart[blockIdx.x] = fmaxf(fmaxf(red[0], red[1]), fmaxf(red[2], red[3]));
}

// bnp layout (floats): [0:64)=sc1 [64:128)=sh1 [128:192)=scs [192:256)=shs
// [256:384)=sc2 [384:512)=sh2 [512]=c1 [513]=c2  (c = 15/(2 tanh(max|w|)))
__global__ void k_bnprep(const float* g1, const float* b1, const float* m1, const float* v1,
                         const float* g2, const float* b2, const float* m2, const float* v2,
                         const float* gs, const float* bs, const float* ms, const float* vs,
                         const float* __restrict__ wpart, float* bnp) {
    int c = threadIdx.x;  // blockDim = 128
    if (c < 64) {
        float s = g1[c] * rsqrtf(v1[c] + EPSV);
        bnp[c] = s;          bnp[64 + c] = b1[c] - m1[c] * s;
        float s2 = gs[c] * rsqrtf(vs[c] + EPSV);
        bnp[128 + c] = s2;   bnp[192 + c] = bs[c] - ms[c] * s2;
    }
    float s = g2[c] * rsqrtf(v2[c] + EPSV);
    bnp[256 + c] = s;        bnp[384 + c] = b2[c] - m2[c] * s;
    if (c < 2) {
        float m = 0.f;
#pragma unroll
        for (int i = 0; i < 16; ++i) m = fmaxf(m, wpart[c * 16 + i]);
        bnp[512 + c] = 15.f / (2.f * tanhf(m));
    }
}

// All weight packs in one dispatch (grid 896):
//  b<288 : w1 -> i8 [(s*128+co)*64+kk], k=s*64+kk, k-order khw*64+ci
//  b<864 : w2 -> i8 same with CIN=128
//  else  : wsw -> bf16 [(s*128+co)*32+kk] (1x1: k=ci), unquantized
__global__ __launch_bounds__(256) void k_wq_all(
        const float* __restrict__ w1, const float* __restrict__ w2,
        const float* __restrict__ wsw,
        signed char* __restrict__ w1qi, signed char* __restrict__ w2qi,
        __bf16* __restrict__ wsq, const float* __restrict__ bnp) {
    int b = blockIdx.x, t = threadIdx.x;
    if (b < 864) {
        bool isw1 = b < 288;
        int idx = (isw1 ? b : b - 288) * 256 + t;
        float c = bnp[512 + (isw1 ? 0 : 1)];
        int kk = idx & 63;
        int co = (idx >> 6) & 127;
        int s = idx >> 13;
        int k = s * 64 + kk;
        int khw, ci;
        const float* src;
        if (isw1) { khw = k >> 6; ci = k & 63;  src = w1 + (co * 64 + ci) * 9 + khw; }
        else      { khw = k >> 7; ci = k & 127; src = w2 + (co * 128 + ci) * 9 + khw; }
        int j = (int)rintf(tanhf(*src) * c + 7.5f);
        (isw1 ? w1qi : w2qi)[idx] = (signed char)(2 * j - 15);
    } else {
        int idx = (b - 864) * 256 + t;
        int kk = idx & 31;
        int co = (idx >> 5) & 127;
        int s = idx >> 12;
        wsq[idx] = (__bf16)wsw[co * 64 + s * 32 + kk];
    }
}

// ---- mega kernel: one image per block ----
__global__ __launch_bounds__(1024, 4) void k_mega(
        const float* __restrict__ x,
        const signed char* __restrict__ w1qi,
        const signed char* __restrict__ w2qi,
        const __bf16* __restrict__ wsq,
        const float* __restrict__ bnp,
        float* __restrict__ out) {
    // LDS: slab 34*34*64 = 73984 | a2p 18*18*128 = 41472 | asc 256*128 = 32768
    __shared__ __align__(16) char lds_all[73984 + 41472 + 32768];
    signed char* slab = (signed char*)lds_all;
    signed char* a2p  = (signed char*)(lds_all + 73984);
    char*        ascb = lds_all + 73984 + 41472;

    const int t = threadIdx.x;
    const int n = blockIdx.x;
    const int wv = t >> 6, l = t & 63;
    const int lrow = l & 15, quad = l >> 4;

    // ---- P1a: zero borders ----
    if (t < 528) {                       // slab: 132 border cells x 4 chunks
        int ci_ = t >> 2, sub = t & 3;
        int cell;
        if (ci_ < 34)      cell = ci_;                    // ph = 0
        else if (ci_ < 68) cell = 33 * 34 + (ci_ - 34);   // ph = 33
        else { int k = ci_ - 68; cell = (1 + (k >> 1)) * 34 + (k & 1) * 33; }
        *(uint4*)(slab + cell * 64 + sub * 16) = uint4{0u, 0u, 0u, 0u};
    }
    if (t < 544) {                       // a2p: 68 border cells x 8 chunks
        int ci_ = t >> 3, sub = t & 7;
        int cell;
        if (ci_ < 18)      cell = ci_;                    // ph = 0
        else if (ci_ < 36) cell = 17 * 18 + (ci_ - 18);   // ph = 17
        else { int k = ci_ - 36; cell = (1 + (k >> 1)) * 18 + (k & 1) * 17; }
        *(uint4*)(a2p + cell * 128 + sub * 16) = uint4{0u, 0u, 0u, 0u};
    }

    // ---- P1b: x -> bn1+actq -> slab; bn_s -> asc ----
#pragma unroll
    for (int it = 0; it < 4; ++it) {
        int u = t + it * 1024;           // 4096 units: (cq 0..15) x (wq 0..255)
        int wq = u & 255;
        int cq = u >> 8;
        int p0 = wq * 4;
        int h = p0 >> 5, w0 = p0 & 31;
        int c0 = cq * 4;
        float4 s1 = *(const float4*)(bnp + c0);
        float4 h1 = *(const float4*)(bnp + 64 + c0);
        float4 ssv = *(const float4*)(bnp + 128 + c0);
        float4 hsv = *(const float4*)(bnp + 192 + c0);
        const float* s1p = (const float*)&s1;
        const float* h1p = (const float*)&h1;
        const float* ssp = (const float*)&ssv;
        const float* hsp = (const float*)&hsv;
        float4 xr[4];
#pragma unroll
        for (int j = 0; j < 4; ++j)
            xr[j] = *(const float4*)(x + ((size_t)(n * 64 + c0 + j)) * 1024 + p0);
#pragma unroll
        for (int k = 0; k < 4; ++k) {
            unsigned u32 = 0;
#pragma unroll
            for (int j = 0; j < 4; ++j) {
                float xv = ((const float*)&xr[j])[k];
                float v = xv * s1p[j] + h1p[j];
                int q = (int)rintf(fminf(fmaxf(v, 0.f), 1.f) * 15.f);
                u32 |= (unsigned)q << (8 * j);
            }
            int pw = w0 + k + 1, ph = h + 1;
            int cell = ph * 34 + pw;
            int key = (pw >> 1) & 3;
            *(unsigned*)(slab + cell * 64 + (((cq >> 2) ^ key) * 16) + (cq & 3) * 4) = u32;
        }
        if ((h & 1) == 0) {
#pragma unroll
            for (int k = 0; k < 4; k += 2) {
                int w = w0 + k;
                __bf16 bv[4];
#pragma unroll
                for (int j = 0; j < 4; ++j) {
                    float xv = ((const float*)&xr[j])[k];
                    bv[j] = (__bf16)(xv * ssp[j] + hsp[j]);
                }
                int cell = (h >> 1) * 16 + (w >> 1);
                int key = (w >> 1) & 7;
                *(uint2*)(ascb + cell * 128 + (((cq >> 1) ^ key) * 16) + (cq & 1) * 8) =
                    *(uint2*)bv;
            }
        }
    }
    __syncthreads();

    const int wco = wv & 1;              // 2 co-tiles of 64
    const int wpos = wv >> 1;            // 8 pos-tiles (2 h2-rows x 16 w2)

    // ---- P2: conv1 (3x3 s2 p1, CIN=64, 9 K64-steps) -> a2p ----
    {
        i32x4 acc1[4][2] = {};
#pragma unroll
        for (int s = 0; s < 9; ++s) {
            const int kh = s / 3, kw = s % 3;
            i32x4 af[4];
#pragma unroll
            for (int i = 0; i < 4; ++i)
                af[i] = *(const i32x4*)(w1qi +
                    ((s * 128 + wco * 64 + i * 16 + lrow) * 64 + quad * 16));
            i32x4 bf[2];
#pragma unroll
            for (int j = 0; j < 2; ++j) {
                int h2 = wpos * 2 + j;
                int ph = 2 * h2 + kh;
                int pw = 2 * lrow + kw;
                int key = (pw >> 1) & 3;
                bf[j] = *(const i32x4*)(slab + (ph * 34 + pw) * 64 + ((quad ^ key) * 16));
            }
#pragma unroll
            for (int i = 0; i < 4; ++i)
#pragma unroll
                for (int j = 0; j < 2; ++j)
                    acc1[i][j] = __builtin_amdgcn_mfma_i32_16x16x64_i8(af[i], bf[j], acc1[i][j], 0, 0, 0);
        }
        // epilogue: bn2+actq -> a2p ints
#pragma unroll
        for (int i = 0; i < 4; ++i) {
            const int co0 = wco * 64 + i * 16 + quad * 4;
            float4 s2 = *(const float4*)(bnp + 256 + co0);
            float4 h2f = *(const float4*)(bnp + 384 + co0);
            const float* s2p = (const float*)&s2;
            const float* h2p = (const float*)&h2f;
#pragma unroll
            for (int j = 0; j < 2; ++j) {
                int h2 = wpos * 2 + j, w2 = lrow;
                unsigned u32 = 0;
#pragma unroll
                for (int r = 0; r < 4; ++r) {
                    float v = (float)acc1[i][j][r] * (s2p[r] * (1.f / 225.f)) + h2p[r];
                    int q = (int)rintf(fminf(fmaxf(v, 0.f), 1.f) * 15.f);
                    u32 |= (unsigned)q << (8 * r);
                }
                int cell = (h2 + 1) * 18 + (w2 + 1);
                int key = (w2 + 1) & 7;
                *(unsigned*)(a2p + cell * 128 + ((((co0 >> 4) ^ key)) * 16) + (co0 & 15)) = u32;
            }
        }
    }
    __syncthreads();

    // ---- P3: conv2 (3x3 s1 p1, CIN=128, 18 K64-steps) + bf16 shortcut ----
    {
        i32x4 acc2[4][2] = {};
#pragma unroll
        for (int s = 0; s < 18; ++s) {
            const int khw = s >> 1, cis = s & 1;
            const int kh = khw / 3, kw = khw % 3;
            i32x4 af[4];
#pragma unroll
            for (int i = 0; i < 4; ++i)
                af[i] = *(const i32x4*)(w2qi +
                    ((s * 128 + wco * 64 + i * 16 + lrow) * 64 + quad * 16));
            i32x4 bf[2];
#pragma unroll
            for (int j = 0; j < 2; ++j) {
                int h2 = wpos * 2 + j;
                int ph = h2 + kh, pw = lrow + kw;
                int chunk = cis * 4 + quad;
                int key = pw & 7;
                bf[j] = *(const i32x4*)(a2p + (ph * 18 + pw) * 128 + ((chunk ^ key) * 16));
            }
#pragma unroll
            for (int i = 0; i < 4; ++i)
#pragma unroll
                for (int j = 0; j < 2; ++j)
                    acc2[i][j] = __builtin_amdgcn_mfma_i32_16x16x64_i8(af[i], bf[j], acc2[i][j], 0, 0, 0);
        }
        f32x4 accM[4][2];
#pragma unroll
        for (int i = 0; i < 4; ++i)
#pragma unroll
            for (int j = 0; j < 2; ++j)
#pragma unroll
                for (int r = 0; r < 4; ++r)
                    accM[i][j][r] = (float)acc2[i][j][r] * (1.f / 225.f);
        // shortcut: 2 bf16 K32-steps from asc, C-in = accM
#pragma unroll
        for (int s = 0; s < 2; ++s) {
            bf16x8 af[4], bb[2];
#pragma unroll
            for (int i = 0; i < 4; ++i)
                af[i] = *(const bf16x8*)(wsq + (size_t)s * 4096 +
                    ((wco * 64 + i * 16 + lrow) * 32 + quad * 8));
#pragma unroll
            for (int j = 0; j < 2; ++j) {
                int h2 = wpos * 2 + j, w2 = lrow;
                int cell = h2 * 16 + w2;
                int sub = s * 4 + quad;
                bb[j] = *(const bf16x8*)(ascb + cell * 128 + ((sub ^ (w2 & 7)) * 16));
            }
#pragma unroll
            for (int i = 0; i < 4; ++i)
#pragma unroll
                for (int j = 0; j < 2; ++j)
                    accM[i][j] = __builtin_amdgcn_mfma_f32_16x16x32_bf16(af[i], bb[j], accM[i][j], 0, 0, 0);
        }
        // store out fp32 NCHW
#pragma unroll
        for (int i = 0; i < 4; ++i) {
            const int co0 = wco * 64 + i * 16 + quad * 4;
#pragma unroll
            for (int j = 0; j < 2; ++j) {
                int pos = (wpos * 2 + j) * 16 + lrow;
#pragma unroll
                for (int r = 0; r < 4; ++r)
                    out[((size_t)n * 128 + co0 + r) * 256 + pos] = accM[i][j][r];
            }
        }
    }
}

extern "C" void kernel_launch(void* const* d_in, const int* in_sizes, int n_in,
                              void* d_out, int out_size, void* d_ws, size_t ws_size,
                              hipStream_t stream) {
    const float* x   = (const float*)d_in[0];
    const float* w1  = (const float*)d_in[1];
    const float* w2  = (const float*)d_in[2];
    const float* wsw = (const float*)d_in[3];
    const float* g1  = (const float*)d_in[4];
    const float* b1  = (const float*)d_in[5];
    const float* m1  = (const float*)d_in[6];
    const float* v1  = (const float*)d_in[7];
    const float* g2  = (const float*)d_in[8];
    const float* b2  = (const float*)d_in[9];
    const float* m2  = (const float*)d_in[10];
    const float* v2  = (const float*)d_in[11];
    const float* gs  = (const float*)d_in[12];
    const float* bs  = (const float*)d_in[13];
    const float* ms  = (const float*)d_in[14];
    const float* vs  = (const float*)d_in[15];
    float* out = (float*)d_out;
    char* ws = (char*)d_ws;

    // ws layout (bytes), ~256 KB total
    signed char* w1qi = (signed char*)(ws);                 // 73,728 i8
    signed char* w2qi = (signed char*)(ws + 73728);         // 147,456 i8
    __bf16*      wsq  = (__bf16*)(ws + 221184);             // 8,192 bf16
    float*       bnp  = (float*)(ws + 237568);              // 514 floats
    float*       wprt = (float*)(ws + 240128);              // 32 floats

    k_wmax<<<32, 256, 0, stream>>>(w1, w2, wprt);
    k_bnprep<<<1, 128, 0, stream>>>(g1, b1, m1, v1, g2, b2, m2, v2,
                                    gs, bs, ms, vs, wprt, bnp);
    k_wq_all<<<896, 256, 0, stream>>>(w1, w2, wsw, w1qi, w2qi, wsq, bnp);
    k_mega<<<256, 1024, 0, stream>>>(x, w1qi, w2qi, wsq, bnp, out);
}